// Round 2
// baseline (268.108 us; speedup 1.0000x reference)
//
#include <hip/hip_runtime.h>

#define D 16
#define WQT 8        // q-tiles (of 16 queries) per wave -> 128 queries/wave
#define NCHUNK 512   // n-tile chunks (grid.y)

#define LOG2E 1.4426950408889634f
#define LN2   0.6931471805599453f

typedef __attribute__((ext_vector_type(8))) short bf16x8;
typedef __attribute__((ext_vector_type(4))) float f32x4;

__device__ __forceinline__ unsigned short f2bf(float f) {
    unsigned u = __float_as_uint(f);
    unsigned r = (u + 0x7fffu + ((u >> 16) & 1u)) >> 16;
    return (unsigned short)r;
}
__device__ __forceinline__ float bf2f(unsigned short h) {
    return __uint_as_float(((unsigned)h) << 16);
}

// ---------------- sum of weights ----------------
__global__ void sumw_kernel(const float* __restrict__ w, int n, float* __restrict__ out) {
    float s = 0.f;
    for (int i = blockIdx.x * blockDim.x + threadIdx.x; i < n; i += gridDim.x * blockDim.x)
        s += w[i];
    #pragma unroll
    for (int off = 32; off > 0; off >>= 1) s += __shfl_down(s, off, 64);
    __shared__ float ls[4];
    int lane = threadIdx.x & 63, wv = threadIdx.x >> 6;
    if (lane == 0) ls[wv] = s;
    __syncthreads();
    if (threadIdx.x == 0) {
        float t = ls[0] + ls[1] + ls[2] + ls[3];
        atomicAdd(out, t);
    }
}

// ---------------- density partials via MFMA ----------------
// S[q][n] = L*(x_q . d_n) - 0.5*L*|d_n|^2 + log2(w_n)  computed as
//   MFMA( A=[yhi|ylo], B1=[dhi|dhi], C=cn ) then MFMA( A, B2=[dlo|0], . )
// acc[q] += sum_n exp2(S[q][n]);  per-query exp2(-0.5*L*|x_q|^2) applied in fin.
__global__ __launch_bounds__(256) void dens_kernel(
        const float* __restrict__ X, const float* __restrict__ data,
        const float* __restrict__ w, float* __restrict__ acc, int Q, int N) {
    const int lane = threadIdx.x & 63;
    const int wave = threadIdx.x >> 6;
    const int col  = lane & 15;        // MFMA row/col index (A: m, B: n, C/D: n)
    const int quad = lane >> 4;        // k-slice group
    const int koff = (quad & 1) * 8;   // k offset of this lane's 8-element slice

    const int qg = blockIdx.x * 4 + wave;   // wave q-group: 128 queries each

    // ---- A fragments: y = L*x split into bf16 hi (quads 0,1) / lo (quads 2,3)
    bf16x8 afrag[WQT];
    #pragma unroll
    for (int t = 0; t < WQT; t++) {
        int q = (qg * WQT + t) * 16 + col;
        const float* xp = X + (size_t)q * D + koff;
        bf16x8 a;
        #pragma unroll
        for (int j = 0; j < 8; j++) {
            float y = xp[j] * LOG2E;
            unsigned short hi = f2bf(y);
            a[j] = (quad < 2) ? (short)hi : (short)f2bf(y - bf2f(hi));
        }
        afrag[t] = a;
    }

    float dens[WQT][4];
    #pragma unroll
    for (int t = 0; t < WQT; t++)
        #pragma unroll
        for (int r = 0; r < 4; r++) dens[t][r] = 0.f;

    // ---- n-chunk: tiles of 16 points
    const int NT = N >> 4;                       // 6250
    const int base = NT / NCHUNK, rem = NT % NCHUNK;
    const int chunk = blockIdx.y;
    int tile0 = chunk * base + min(chunk, rem);
    int cnt = base + (chunk < rem ? 1 : 0);

    for (int it = 0; it < cnt; it++) {
        int tile = tile0 + it;
        int n = tile * 16 + col;
        const float* dp = data + (size_t)n * D + koff;

        // build B fragments in-register (bf16 hi/lo split) + cn
        bf16x8 b1, b2;
        float dd = 0.f;
        #pragma unroll
        for (int j = 0; j < 8; j++) {
            float v = dp[j];
            dd = fmaf(v, v, dd);
            unsigned short hi = f2bf(v);
            b1[j] = (short)hi;
            b2[j] = (quad < 2) ? (short)f2bf(v - bf2f(hi)) : (short)0;
        }
        dd += __shfl_xor(dd, 16, 64);            // combine the two 8-element halves
        float cn = fmaf(-0.5f * LOG2E, dd, __builtin_amdgcn_logf(w[n]));
        f32x4 cvec = {cn, cn, cn, cn};

        #pragma unroll
        for (int t = 0; t < WQT; t++) {
            f32x4 s = __builtin_amdgcn_mfma_f32_16x16x32_bf16(afrag[t], b1, cvec, 0, 0, 0);
            s = __builtin_amdgcn_mfma_f32_16x16x32_bf16(afrag[t], b2, s, 0, 0, 0);
            #pragma unroll
            for (int r = 0; r < 4; r++)
                dens[t][r] += __builtin_amdgcn_exp2f(s[r]);
        }
    }

    // ---- reduce over the 16 column-lanes, then one atomic per (q)
    #pragma unroll
    for (int t = 0; t < WQT; t++) {
        #pragma unroll
        for (int r = 0; r < 4; r++) {
            float v = dens[t][r];
            v += __shfl_xor(v, 1, 64);
            v += __shfl_xor(v, 2, 64);
            v += __shfl_xor(v, 4, 64);
            v += __shfl_xor(v, 8, 64);
            if (col == 0) {
                int q = (qg * WQT + t) * 16 + quad * 4 + r;
                atomicAdd(&acc[q], v);
            }
        }
    }
}

// ---------------- finalize: log density ----------------
__global__ void fin_kernel(const float* __restrict__ X, const float* __restrict__ acc,
                           const float* __restrict__ sumw, float* __restrict__ out, int Q) {
    int q = blockIdx.x * blockDim.x + threadIdx.x;
    if (q >= Q) return;
    float xx = 0.f;
    #pragma unroll
    for (int k = 0; k < D; k++) {
        float v = X[(size_t)q * D + k];
        xx += v * v;
    }
    float aq = -0.5f * LOG2E * xx;                     // log2 of per-query factor
    const float ln_norm = -8.f * 1.8378770664093453f;  // ln((2*pi)^-8)
    float ld = LN2 * (aq + __builtin_amdgcn_logf(acc[q]) - __builtin_amdgcn_logf(sumw[0])) + ln_norm;
    out[q] = ld;
}

extern "C" void kernel_launch(void* const* d_in, const int* in_sizes, int n_in,
                              void* d_out, int out_size, void* d_ws, size_t ws_size,
                              hipStream_t stream) {
    const float* X    = (const float*)d_in[0];
    const float* data = (const float*)d_in[1];
    const float* w    = (const float*)d_in[2];
    float* out = (float*)d_out;
    int Q = in_sizes[0] / D;   // 2048
    int N = in_sizes[1] / D;   // 100000

    float* sumw = (float*)d_ws;
    float* acc  = sumw + 1;

    hipMemsetAsync(d_ws, 0, (size_t)(1 + Q) * sizeof(float), stream);

    sumw_kernel<<<64, 256, 0, stream>>>(w, N, sumw);

    // grid.x: q-groups/4 (each block = 4 waves, each wave covers WQT*16=128 queries)
    dim3 grid(Q / (4 * WQT * 16), NCHUNK);
    dens_kernel<<<grid, 256, 0, stream>>>(X, data, w, acc, Q, N);

    fin_kernel<<<(Q + 255) / 256, 256, 0, stream>>>(X, acc, sumw, out, Q);
}

// Round 3
// 195.642 us; speedup vs baseline: 1.3704x; 1.3704x over previous
//
#include <hip/hip_runtime.h>

#define D 16
#define WQT 8        // q-tiles (of 16 queries) per wave -> 128 queries/wave
#define NCHUNK 512   // n-dimension grid split

#define LOG2E 1.4426950408889634f
#define LN2   0.6931471805599453f

typedef __attribute__((ext_vector_type(8))) short bf16x8;
typedef __attribute__((ext_vector_type(4))) float f32x4;

__device__ __forceinline__ unsigned short f2bf(float f) {
    unsigned u = __float_as_uint(f);
    unsigned r = (u + 0x7fffu + ((u >> 16) & 1u)) >> 16;
    return (unsigned short)r;
}
__device__ __forceinline__ float bf2f(unsigned short h) {
    return __uint_as_float(((unsigned)h) << 16);
}

// ---------------- prep: bf16 hi/lo split of data + per-point constant + sumw --------
// hi[n][k], lo[n][k] (bf16, 32B each per point); cn[n] = -0.5*L*|d_n|^2 + log2(w_n)
__global__ void prep_kernel(const float* __restrict__ data, const float* __restrict__ w,
                            int N, float* __restrict__ cn, unsigned* __restrict__ hi,
                            unsigned* __restrict__ lo, float* __restrict__ sumw) {
    int n = blockIdx.x * blockDim.x + threadIdx.x;
    float s = 0.f;
    if (n < N) {
        const float4* dp = (const float4*)(data + (size_t)n * D);
        float v[D];
        #pragma unroll
        for (int r = 0; r < 4; r++) {
            float4 t = dp[r];
            v[4*r+0] = t.x; v[4*r+1] = t.y; v[4*r+2] = t.z; v[4*r+3] = t.w;
        }
        float dd = 0.f;
        unsigned hp[8], lp[8];
        #pragma unroll
        for (int j = 0; j < 8; j++) {
            float a = v[2*j], b = v[2*j+1];
            dd = fmaf(a, a, fmaf(b, b, dd));
            unsigned short ha = f2bf(a), hb = f2bf(b);
            unsigned short la = f2bf(a - bf2f(ha)), lb = f2bf(b - bf2f(hb));
            hp[j] = (unsigned)ha | ((unsigned)hb << 16);
            lp[j] = (unsigned)la | ((unsigned)lb << 16);
        }
        uint4* hq = (uint4*)(hi + (size_t)n * 8);
        uint4* lq = (uint4*)(lo + (size_t)n * 8);
        hq[0] = make_uint4(hp[0], hp[1], hp[2], hp[3]);
        hq[1] = make_uint4(hp[4], hp[5], hp[6], hp[7]);
        lq[0] = make_uint4(lp[0], lp[1], lp[2], lp[3]);
        lq[1] = make_uint4(lp[4], lp[5], lp[6], lp[7]);
        float wn = w[n];
        s = wn;
        cn[n] = fmaf(-0.5f * LOG2E, dd, __builtin_amdgcn_logf(wn));
    }
    #pragma unroll
    for (int off = 32; off > 0; off >>= 1) s += __shfl_down(s, off, 64);
    __shared__ float ls[4];
    int lane = threadIdx.x & 63, wv = threadIdx.x >> 6;
    if (lane == 0) ls[wv] = s;
    __syncthreads();
    if (threadIdx.x == 0) atomicAdd(sumw, ls[0] + ls[1] + ls[2] + ls[3]);
}

// ---------------- density partials via MFMA ----------------
// S[q][n] = MFMA(A=[yhi|ylo], B1=[dhi|dhi], C=cn) then MFMA(A, B2=[dlo|dlo], .)
// acc[q] += sum_n exp2(S[q][n])
__global__ __launch_bounds__(256, 4) void dens_kernel(
        const float* __restrict__ X, const unsigned short* __restrict__ hi,
        const unsigned short* __restrict__ lo, const float* __restrict__ cn,
        float* __restrict__ acc, int Q, int N) {
    const int lane = threadIdx.x & 63;
    const int wave = threadIdx.x >> 6;
    const int col  = lane & 15;        // A: m-index; C/D: n-index
    const int quad = lane >> 4;
    const int koff = (quad & 1) * 8;

    const int qg = blockIdx.x * 4 + wave;   // 128 queries per wave

    // ---- A fragments: y = L*x split into bf16 hi (quads 0,1) / lo (quads 2,3)
    bf16x8 afrag[WQT];
    #pragma unroll
    for (int t = 0; t < WQT; t++) {
        int q = (qg * WQT + t) * 16 + col;
        const float* xp = X + (size_t)q * D + koff;
        bf16x8 a;
        #pragma unroll
        for (int j = 0; j < 8; j++) {
            float y = xp[j] * LOG2E;
            unsigned short h = f2bf(y);
            a[j] = (quad < 2) ? (short)h : (short)f2bf(y - bf2f(h));
        }
        afrag[t] = a;
    }

    float dens[WQT][4];
    #pragma unroll
    for (int t = 0; t < WQT; t++)
        #pragma unroll
        for (int r = 0; r < 4; r++) dens[t][r] = 0.f;

    // ---- this block's n-tile range (tiles of 16 points)
    const int NT = N >> 4;                       // 6250
    const int base = NT / NCHUNK, rem = NT % NCHUNK;
    const int chunk = blockIdx.y;
    int tile0 = chunk * base + min(chunk, rem);
    int cnt = base + (chunk < rem ? 1 : 0);

    // per-lane element offsets (in shorts): point n = tile*16+col, k-slice koff
    size_t eoff = ((size_t)col << 4) + koff;

    // prefetch first tile
    int n0 = (tile0 << 4) + col;
    bf16x8 b1 = *(const bf16x8*)(hi + ((size_t)tile0 << 8) + eoff);
    bf16x8 b2 = *(const bf16x8*)(lo + ((size_t)tile0 << 8) + eoff);
    float  c0 = cn[n0];

    for (int it = 0; it < cnt; it++) {
        int tile = tile0 + it;
        // prefetch next tile (unconditional; one-past-end lands in adjacent ws
        // region — garbage but never consumed)
        bf16x8 nb1 = *(const bf16x8*)(hi + (((size_t)tile + 1) << 8) + eoff);
        bf16x8 nb2 = *(const bf16x8*)(lo + (((size_t)tile + 1) << 8) + eoff);
        float  nc0 = cn[(tile + 1) * 16 + col];

        f32x4 cvec = {c0, c0, c0, c0};
        #pragma unroll
        for (int t = 0; t < WQT; t++) {
            f32x4 s = __builtin_amdgcn_mfma_f32_16x16x32_bf16(afrag[t], b1, cvec, 0, 0, 0);
            s = __builtin_amdgcn_mfma_f32_16x16x32_bf16(afrag[t], b2, s, 0, 0, 0);
            #pragma unroll
            for (int r = 0; r < 4; r++)
                dens[t][r] += __builtin_amdgcn_exp2f(s[r]);
        }
        b1 = nb1; b2 = nb2; c0 = nc0;
    }

    // ---- reduce over the 16 n-lanes, then one atomic per q
    #pragma unroll
    for (int t = 0; t < WQT; t++) {
        #pragma unroll
        for (int r = 0; r < 4; r++) {
            float v = dens[t][r];
            v += __shfl_xor(v, 1, 64);
            v += __shfl_xor(v, 2, 64);
            v += __shfl_xor(v, 4, 64);
            v += __shfl_xor(v, 8, 64);
            if (col == 0) {
                int q = (qg * WQT + t) * 16 + quad * 4 + r;
                atomicAdd(&acc[q], v);
            }
        }
    }
}

// ---------------- finalize: log density ----------------
__global__ void fin_kernel(const float* __restrict__ X, const float* __restrict__ acc,
                           const float* __restrict__ sumw, float* __restrict__ out, int Q) {
    int q = blockIdx.x * blockDim.x + threadIdx.x;
    if (q >= Q) return;
    float xx = 0.f;
    #pragma unroll
    for (int k = 0; k < D; k++) {
        float v = X[(size_t)q * D + k];
        xx += v * v;
    }
    float aq = -0.5f * LOG2E * xx;
    const float ln_norm = -8.f * 1.8378770664093453f;  // ln((2*pi)^-8)
    float ld = LN2 * (aq + __builtin_amdgcn_logf(acc[q]) - __builtin_amdgcn_logf(sumw[0])) + ln_norm;
    out[q] = ld;
}

extern "C" void kernel_launch(void* const* d_in, const int* in_sizes, int n_in,
                              void* d_out, int out_size, void* d_ws, size_t ws_size,
                              hipStream_t stream) {
    const float* X    = (const float*)d_in[0];
    const float* data = (const float*)d_in[1];
    const float* w    = (const float*)d_in[2];
    float* out = (float*)d_out;
    int Q = in_sizes[0] / D;   // 2048
    int N = in_sizes[1] / D;   // 100000

    // workspace layout (floats): [0]=sumw, [64..64+Q)=acc, [2112..2112+N)=cn,
    // then hi (N*8 uints), then lo (N*8 uints)
    float* base = (float*)d_ws;
    float* sumw = base;
    float* acc  = base + 64;
    float* cnb  = base + 64 + Q;                 // base+2112
    unsigned* hi = (unsigned*)(cnb + N);
    unsigned* lo = hi + (size_t)N * 8;

    hipMemsetAsync(d_ws, 0, (size_t)(64 + Q) * sizeof(float), stream);

    prep_kernel<<<(N + 255) / 256, 256, 0, stream>>>(data, w, N, cnb, hi, lo, sumw);

    dim3 grid(Q / (4 * WQT * 16), NCHUNK);
    dens_kernel<<<grid, 256, 0, stream>>>(X, (const unsigned short*)hi,
                                          (const unsigned short*)lo, cnb, acc, Q, N);

    fin_kernel<<<(Q + 255) / 256, 256, 0, stream>>>(X, acc, sumw, out, Q);
}

// Round 4
// 140.226 us; speedup vs baseline: 1.9120x; 1.3952x over previous
//
#include <hip/hip_runtime.h>

#define D 16
#define WQT 4        // q-tiles (of 16 queries) per wave -> 64 queries/wave
#define NCHUNK 256   // n-dimension grid split (also partial-buffer depth)

#define LOG2E 1.4426950408889634f
#define LN2   0.6931471805599453f

typedef __attribute__((ext_vector_type(8))) short bf16x8;
typedef __attribute__((ext_vector_type(4))) float f32x4;

__device__ __forceinline__ unsigned short f2bf(float f) {
    unsigned u = __float_as_uint(f);
    unsigned r = (u + 0x7fffu + ((u >> 16) & 1u)) >> 16;
    return (unsigned short)r;
}
__device__ __forceinline__ float bf2f(unsigned short h) {
    return __uint_as_float(((unsigned)h) << 16);
}

// ---------------- prep: bf16 hi/lo split of data + per-point constant + sumw --------
__global__ void prep_kernel(const float* __restrict__ data, const float* __restrict__ w,
                            int N, float* __restrict__ cn, unsigned* __restrict__ hi,
                            unsigned* __restrict__ lo, float* __restrict__ sumw) {
    int n = blockIdx.x * blockDim.x + threadIdx.x;
    float s = 0.f;
    if (n < N) {
        const float4* dp = (const float4*)(data + (size_t)n * D);
        float v[D];
        #pragma unroll
        for (int r = 0; r < 4; r++) {
            float4 t = dp[r];
            v[4*r+0] = t.x; v[4*r+1] = t.y; v[4*r+2] = t.z; v[4*r+3] = t.w;
        }
        float dd = 0.f;
        unsigned hp[8], lp[8];
        #pragma unroll
        for (int j = 0; j < 8; j++) {
            float a = v[2*j], b = v[2*j+1];
            dd = fmaf(a, a, fmaf(b, b, dd));
            unsigned short ha = f2bf(a), hb = f2bf(b);
            unsigned short la = f2bf(a - bf2f(ha)), lb = f2bf(b - bf2f(hb));
            hp[j] = (unsigned)ha | ((unsigned)hb << 16);
            lp[j] = (unsigned)la | ((unsigned)lb << 16);
        }
        uint4* hq = (uint4*)(hi + (size_t)n * 8);
        uint4* lq = (uint4*)(lo + (size_t)n * 8);
        hq[0] = make_uint4(hp[0], hp[1], hp[2], hp[3]);
        hq[1] = make_uint4(hp[4], hp[5], hp[6], hp[7]);
        lq[0] = make_uint4(lp[0], lp[1], lp[2], lp[3]);
        lq[1] = make_uint4(lp[4], lp[5], lp[6], lp[7]);
        float wn = w[n];
        s = wn;
        cn[n] = fmaf(-0.5f * LOG2E, dd, __builtin_amdgcn_logf(wn));
    }
    #pragma unroll
    for (int off = 32; off > 0; off >>= 1) s += __shfl_down(s, off, 64);
    __shared__ float ls[4];
    int lane = threadIdx.x & 63, wv = threadIdx.x >> 6;
    if (lane == 0) ls[wv] = s;
    __syncthreads();
    if (threadIdx.x == 0) atomicAdd(sumw, ls[0] + ls[1] + ls[2] + ls[3]);
}

// ---------------- density partials via MFMA (no atomics) ----------------
// part[chunk][q] = sum_{n in chunk} exp2( L*(x_q.d_n) - 0.5*L*|d_n|^2 + log2 w_n )
__global__ __launch_bounds__(256, 4) void dens_kernel(
        const float* __restrict__ X, const unsigned short* __restrict__ hi,
        const unsigned short* __restrict__ lo, const float* __restrict__ cn,
        float* __restrict__ part, int Q, int N) {
    const int lane = threadIdx.x & 63;
    const int wave = threadIdx.x >> 6;
    const int col  = lane & 15;        // A: m-index; C/D: n-index
    const int quad = lane >> 4;
    const int koff = (quad & 1) * 8;

    const int qg = blockIdx.x * 4 + wave;   // 64 queries per wave

    // ---- A fragments: y = L*x, bf16 hi (quads 0,1) / lo residual (quads 2,3)
    bf16x8 afrag[WQT];
    #pragma unroll
    for (int t = 0; t < WQT; t++) {
        int q = (qg * WQT + t) * 16 + col;
        const float* xp = X + (size_t)q * D + koff;
        bf16x8 a;
        #pragma unroll
        for (int j = 0; j < 8; j++) {
            float y = xp[j] * LOG2E;
            unsigned short h = f2bf(y);
            a[j] = (quad < 2) ? (short)h : (short)f2bf(y - bf2f(h));
        }
        afrag[t] = a;
    }

    float dens[WQT][4];
    #pragma unroll
    for (int t = 0; t < WQT; t++)
        #pragma unroll
        for (int r = 0; r < 4; r++) dens[t][r] = 0.f;

    // ---- this block's n-tile range (tiles of 16 points)
    const int NT = N >> 4;                       // 6250
    const int base = NT / NCHUNK, rem = NT % NCHUNK;
    const int chunk = blockIdx.y;
    int tile0 = chunk * base + min(chunk, rem);
    int cnt = base + (chunk < rem ? 1 : 0);

    size_t eoff = ((size_t)col << 4) + koff;

    // depth-1 register prefetch (one-past-end prefetch lands in the adjacent
    // ws region — garbage but never consumed)
    bf16x8 b1 = *(const bf16x8*)(hi + ((size_t)tile0 << 8) + eoff);
    bf16x8 b2 = *(const bf16x8*)(lo + ((size_t)tile0 << 8) + eoff);
    float  c0 = cn[(tile0 << 4) + col];

    for (int it = 0; it < cnt; it++) {
        int tile = tile0 + it;
        bf16x8 nb1 = *(const bf16x8*)(hi + (((size_t)tile + 1) << 8) + eoff);
        bf16x8 nb2 = *(const bf16x8*)(lo + (((size_t)tile + 1) << 8) + eoff);
        float  nc0 = cn[(tile + 1) * 16 + col];

        f32x4 cvec = {c0, c0, c0, c0};
        #pragma unroll
        for (int t = 0; t < WQT; t++) {
            f32x4 s = __builtin_amdgcn_mfma_f32_16x16x32_bf16(afrag[t], b1, cvec, 0, 0, 0);
            s = __builtin_amdgcn_mfma_f32_16x16x32_bf16(afrag[t], b2, s, 0, 0, 0);
            #pragma unroll
            for (int r = 0; r < 4; r++)
                dens[t][r] += __builtin_amdgcn_exp2f(s[r]);
        }
        b1 = nb1; b2 = nb2; c0 = nc0;
    }

    // ---- reduce over the 16 n-lanes, plain store (one slot per chunk, no atomics)
    #pragma unroll
    for (int t = 0; t < WQT; t++) {
        #pragma unroll
        for (int r = 0; r < 4; r++) {
            float v = dens[t][r];
            v += __shfl_xor(v, 1, 64);
            v += __shfl_xor(v, 2, 64);
            v += __shfl_xor(v, 4, 64);
            v += __shfl_xor(v, 8, 64);
            if (col == 0) {
                int q = (qg * WQT + t) * 16 + quad * 4 + r;
                part[(size_t)chunk * Q + q] = v;
            }
        }
    }
}

// ---------------- finalize: reduce chunks + log density ----------------
__global__ void fin_kernel(const float* __restrict__ X, const float* __restrict__ part,
                           const float* __restrict__ sumw, float* __restrict__ out, int Q) {
    int q = blockIdx.x * blockDim.x + threadIdx.x;
    if (q >= Q) return;
    float a0 = 0.f, a1 = 0.f, a2 = 0.f, a3 = 0.f;
    #pragma unroll 4
    for (int c = 0; c < NCHUNK; c += 4) {
        a0 += part[(size_t)(c + 0) * Q + q];
        a1 += part[(size_t)(c + 1) * Q + q];
        a2 += part[(size_t)(c + 2) * Q + q];
        a3 += part[(size_t)(c + 3) * Q + q];
    }
    float dsum = (a0 + a1) + (a2 + a3);
    float xx = 0.f;
    #pragma unroll
    for (int k = 0; k < D; k++) {
        float v = X[(size_t)q * D + k];
        xx += v * v;
    }
    float aq = -0.5f * LOG2E * xx;
    const float ln_norm = -8.f * 1.8378770664093453f;  // ln((2*pi)^-8)
    float ld = LN2 * (aq + __builtin_amdgcn_logf(dsum) - __builtin_amdgcn_logf(sumw[0])) + ln_norm;
    out[q] = ld;
}

extern "C" void kernel_launch(void* const* d_in, const int* in_sizes, int n_in,
                              void* d_out, int out_size, void* d_ws, size_t ws_size,
                              hipStream_t stream) {
    const float* X    = (const float*)d_in[0];
    const float* data = (const float*)d_in[1];
    const float* w    = (const float*)d_in[2];
    float* out = (float*)d_out;
    int Q = in_sizes[0] / D;   // 2048
    int N = in_sizes[1] / D;   // 100000

    // ws layout (floats): [0..64) sumw, [64..64+N) cn, then hi (N*8 u32),
    // lo (N*8 u32), then part (NCHUNK*Q floats)
    float* base = (float*)d_ws;
    float* sumw = base;
    float* cnb  = base + 64;
    unsigned* hi = (unsigned*)(cnb + N);
    unsigned* lo = hi + (size_t)N * 8;
    float* part = (float*)(lo + (size_t)N * 8);

    hipMemsetAsync(d_ws, 0, 64 * sizeof(float), stream);

    prep_kernel<<<(N + 255) / 256, 256, 0, stream>>>(data, w, N, cnb, hi, lo, sumw);

    dim3 grid(Q / (4 * WQT * 16), NCHUNK);   // (8, 256)
    dens_kernel<<<grid, 256, 0, stream>>>(X, (const unsigned short*)hi,
                                          (const unsigned short*)lo, cnb, part, Q, N);

    fin_kernel<<<(Q + 255) / 256, 256, 0, stream>>>(X, part, sumw, out, Q);
}

// Round 5
// 135.747 us; speedup vs baseline: 1.9751x; 1.0330x over previous
//
#include <hip/hip_runtime.h>

#define D 16
#define WQT 4        // q-tiles (of 16 queries) per wave -> 64 queries/wave
#define NCHUNK 256   // n-dimension grid split (also partial-buffer depth)
#define TILES_MAX 25 // ceil(6250/256)

#define LOG2E 1.4426950408889634f
#define LN2   0.6931471805599453f

typedef __attribute__((ext_vector_type(8))) short bf16x8;
typedef __attribute__((ext_vector_type(4))) float f32x4;

__device__ __forceinline__ unsigned short f2bf(float f) {
    unsigned u = __float_as_uint(f);
    unsigned r = (u + 0x7fffu + ((u >> 16) & 1u)) >> 16;
    return (unsigned short)r;
}
__device__ __forceinline__ float bf2f(unsigned short h) {
    return __uint_as_float(((unsigned)h) << 16);
}

// ---------------- prep: bf16 hi/lo split of data + per-point constant + sumw --------
__global__ void prep_kernel(const float* __restrict__ data, const float* __restrict__ w,
                            int N, float* __restrict__ cn, unsigned* __restrict__ hi,
                            unsigned* __restrict__ lo, float* __restrict__ sumw) {
    int n = blockIdx.x * blockDim.x + threadIdx.x;
    float s = 0.f;
    if (n < N) {
        const float4* dp = (const float4*)(data + (size_t)n * D);
        float v[D];
        #pragma unroll
        for (int r = 0; r < 4; r++) {
            float4 t = dp[r];
            v[4*r+0] = t.x; v[4*r+1] = t.y; v[4*r+2] = t.z; v[4*r+3] = t.w;
        }
        float dd = 0.f;
        unsigned hp[8], lp[8];
        #pragma unroll
        for (int j = 0; j < 8; j++) {
            float a = v[2*j], b = v[2*j+1];
            dd = fmaf(a, a, fmaf(b, b, dd));
            unsigned short ha = f2bf(a), hb = f2bf(b);
            unsigned short la = f2bf(a - bf2f(ha)), lb = f2bf(b - bf2f(hb));
            hp[j] = (unsigned)ha | ((unsigned)hb << 16);
            lp[j] = (unsigned)la | ((unsigned)lb << 16);
        }
        uint4* hq = (uint4*)(hi + (size_t)n * 8);
        uint4* lq = (uint4*)(lo + (size_t)n * 8);
        hq[0] = make_uint4(hp[0], hp[1], hp[2], hp[3]);
        hq[1] = make_uint4(hp[4], hp[5], hp[6], hp[7]);
        lq[0] = make_uint4(lp[0], lp[1], lp[2], lp[3]);
        lq[1] = make_uint4(lp[4], lp[5], lp[6], lp[7]);
        float wn = w[n];
        s = wn;
        cn[n] = fmaf(-0.5f * LOG2E, dd, __builtin_amdgcn_logf(wn));
    }
    #pragma unroll
    for (int off = 32; off > 0; off >>= 1) s += __shfl_down(s, off, 64);
    __shared__ float ls[4];
    int lane = threadIdx.x & 63, wv = threadIdx.x >> 6;
    if (lane == 0) ls[wv] = s;
    __syncthreads();
    if (threadIdx.x == 0) atomicAdd(sumw, ls[0] + ls[1] + ls[2] + ls[3]);
}

// ---------------- density partials via MFMA, B-tiles staged in LDS ----------------
// part[chunk][q] = sum_{n in chunk} exp2( L*(x_q.d_n) - 0.5*L*|d_n|^2 + log2 w_n )
__global__ __launch_bounds__(256, 4) void dens_kernel(
        const float* __restrict__ X, const unsigned short* __restrict__ hi,
        const unsigned short* __restrict__ lo, const float* __restrict__ cn,
        float* __restrict__ part, int Q, int N) {
    __shared__ unsigned short sh_hi[TILES_MAX * 256];  // 12.8 KB
    __shared__ unsigned short sh_lo[TILES_MAX * 256];  // 12.8 KB
    __shared__ float          sh_cn[TILES_MAX * 16];   // 1.6 KB

    const int lane = threadIdx.x & 63;
    const int wave = threadIdx.x >> 6;
    const int col  = lane & 15;        // A: m-index; C/D: n-index
    const int quad = lane >> 4;
    const int koff = (quad & 1) * 8;

    const int qg = blockIdx.x * 4 + wave;   // 64 queries per wave

    // ---- this block's n-tile range (tiles of 16 points)
    const int NT = N >> 4;                       // 6250
    const int base = NT / NCHUNK, rem = NT % NCHUNK;
    const int chunk = blockIdx.y;
    const int tile0 = chunk * base + min(chunk, rem);
    const int cnt = base + (chunk < rem ? 1 : 0);

    // ---- stage chunk slice into LDS (coalesced 16B copies; slice is contiguous)
    {
        const uint4* gh = (const uint4*)(hi + ((size_t)tile0 << 8));
        const uint4* gl = (const uint4*)(lo + ((size_t)tile0 << 8));
        uint4* sh = (uint4*)sh_hi;
        uint4* sl = (uint4*)sh_lo;
        int nvec = cnt * 32;                     // cnt*512B / 16B
        for (int i = threadIdx.x; i < nvec; i += 256) {
            sh[i] = gh[i];
            sl[i] = gl[i];
        }
        const float* gc = cn + (tile0 << 4);
        for (int i = threadIdx.x; i < cnt * 16; i += 256)
            sh_cn[i] = gc[i];
    }

    // ---- A fragments: y = L*x, bf16 hi (quads 0,1) / lo residual (quads 2,3)
    //      (VALU work overlaps the staging loads above)
    bf16x8 afrag[WQT];
    #pragma unroll
    for (int t = 0; t < WQT; t++) {
        int q = (qg * WQT + t) * 16 + col;
        const float* xp = X + (size_t)q * D + koff;
        bf16x8 a;
        #pragma unroll
        for (int j = 0; j < 8; j++) {
            float y = xp[j] * LOG2E;
            unsigned short h = f2bf(y);
            a[j] = (quad < 2) ? (short)h : (short)f2bf(y - bf2f(h));
        }
        afrag[t] = a;
    }

    float dens[WQT][4];
    #pragma unroll
    for (int t = 0; t < WQT; t++)
        #pragma unroll
        for (int r = 0; r < 4; r++) dens[t][r] = 0.f;

    __syncthreads();

    // ---- main loop: pure LDS + VALU/MFMA, no global access
    const int eoff = (col << 4) + koff;          // shorts
    for (int it = 0; it < cnt; it++) {
        const bf16x8 b1 = *(const bf16x8*)(sh_hi + it * 256 + eoff);
        const bf16x8 b2 = *(const bf16x8*)(sh_lo + it * 256 + eoff);
        float c0 = sh_cn[it * 16 + col];
        f32x4 cvec = {c0, c0, c0, c0};
        #pragma unroll
        for (int t = 0; t < WQT; t++) {
            f32x4 s = __builtin_amdgcn_mfma_f32_16x16x32_bf16(afrag[t], b1, cvec, 0, 0, 0);
            s = __builtin_amdgcn_mfma_f32_16x16x32_bf16(afrag[t], b2, s, 0, 0, 0);
            #pragma unroll
            for (int r = 0; r < 4; r++)
                dens[t][r] += __builtin_amdgcn_exp2f(s[r]);
        }
    }

    // ---- reduce over the 16 n-lanes, plain store (one slot per chunk, no atomics)
    #pragma unroll
    for (int t = 0; t < WQT; t++) {
        #pragma unroll
        for (int r = 0; r < 4; r++) {
            float v = dens[t][r];
            v += __shfl_xor(v, 1, 64);
            v += __shfl_xor(v, 2, 64);
            v += __shfl_xor(v, 4, 64);
            v += __shfl_xor(v, 8, 64);
            if (col == 0) {
                int q = (qg * WQT + t) * 16 + quad * 4 + r;
                part[(size_t)chunk * Q + q] = v;
            }
        }
    }
}

// ---------------- finalize: reduce chunks + log density ----------------
__global__ void fin_kernel(const float* __restrict__ X, const float* __restrict__ part,
                           const float* __restrict__ sumw, float* __restrict__ out, int Q) {
    int q = blockIdx.x * blockDim.x + threadIdx.x;
    if (q >= Q) return;
    float a0 = 0.f, a1 = 0.f, a2 = 0.f, a3 = 0.f;
    #pragma unroll 4
    for (int c = 0; c < NCHUNK; c += 4) {
        a0 += part[(size_t)(c + 0) * Q + q];
        a1 += part[(size_t)(c + 1) * Q + q];
        a2 += part[(size_t)(c + 2) * Q + q];
        a3 += part[(size_t)(c + 3) * Q + q];
    }
    float dsum = (a0 + a1) + (a2 + a3);
    float xx = 0.f;
    #pragma unroll
    for (int k = 0; k < D; k++) {
        float v = X[(size_t)q * D + k];
        xx += v * v;
    }
    float aq = -0.5f * LOG2E * xx;
    const float ln_norm = -8.f * 1.8378770664093453f;  // ln((2*pi)^-8)
    float ld = LN2 * (aq + __builtin_amdgcn_logf(dsum) - __builtin_amdgcn_logf(sumw[0])) + ln_norm;
    out[q] = ld;
}

extern "C" void kernel_launch(void* const* d_in, const int* in_sizes, int n_in,
                              void* d_out, int out_size, void* d_ws, size_t ws_size,
                              hipStream_t stream) {
    const float* X    = (const float*)d_in[0];
    const float* data = (const float*)d_in[1];
    const float* w    = (const float*)d_in[2];
    float* out = (float*)d_out;
    int Q = in_sizes[0] / D;   // 2048
    int N = in_sizes[1] / D;   // 100000

    // ws layout (floats): [0..64) sumw, [64..64+N) cn, then hi (N*8 u32),
    // lo (N*8 u32), then part (NCHUNK*Q floats)
    float* base = (float*)d_ws;
    float* sumw = base;
    float* cnb  = base + 64;
    unsigned* hi = (unsigned*)(cnb + N);
    unsigned* lo = hi + (size_t)N * 8;
    float* part = (float*)(lo + (size_t)N * 8);

    hipMemsetAsync(d_ws, 0, 64 * sizeof(float), stream);

    prep_kernel<<<(N + 255) / 256, 256, 0, stream>>>(data, w, N, cnb, hi, lo, sumw);

    dim3 grid(Q / (4 * WQT * 16), NCHUNK);   // (8, 256)
    dens_kernel<<<grid, 256, 0, stream>>>(X, (const unsigned short*)hi,
                                          (const unsigned short*)lo, cnb, part, Q, N);

    fin_kernel<<<(Q + 255) / 256, 256, 0, stream>>>(X, part, sumw, out, Q);
}

// Round 6
// 116.895 us; speedup vs baseline: 2.2936x; 1.1613x over previous
//
#include <hip/hip_runtime.h>

#define D 16
#define WQT 4        // q-tiles (of 16 queries) per wave -> 64 queries/wave
#define NCHUNK 192   // n-dimension grid split; 8*192=1536 blocks = 6144 waves = 6/SIMD
#define TILES_MAX 33 // base=32 (+1 for the first `rem` chunks)

#define LOG2E 1.4426950408889634f
#define LN2   0.6931471805599453f

typedef __attribute__((ext_vector_type(8))) short bf16x8;
typedef __attribute__((ext_vector_type(4))) float f32x4;

__device__ __forceinline__ unsigned short f2bf(float f) {
    unsigned u = __float_as_uint(f);
    unsigned r = (u + 0x7fffu + ((u >> 16) & 1u)) >> 16;
    return (unsigned short)r;
}

// ---------------- sum of weights ----------------
__global__ void sumw_kernel(const float* __restrict__ w, int n, float* __restrict__ out) {
    float s = 0.f;
    for (int i = blockIdx.x * blockDim.x + threadIdx.x; i < n; i += gridDim.x * blockDim.x)
        s += w[i];
    #pragma unroll
    for (int off = 32; off > 0; off >>= 1) s += __shfl_down(s, off, 64);
    __shared__ float ls[4];
    int lane = threadIdx.x & 63, wv = threadIdx.x >> 6;
    if (lane == 0) ls[wv] = s;
    __syncthreads();
    if (threadIdx.x == 0) atomicAdd(out, ls[0] + ls[1] + ls[2] + ls[3]);
}

// ---------------- fused convert + density partials via MFMA ----------------
// Stages this chunk's raw fp32 points into LDS as bf16 + cn, then
// part[chunk][q] = sum_{n in chunk} exp2( L*(x_q.d_n) - 0.5*L*|d_n|^2 + log2 w_n )
__global__ __launch_bounds__(256, 6) void dens_kernel(
        const float* __restrict__ X, const float* __restrict__ data,
        const float* __restrict__ w, float* __restrict__ part, int Q, int N) {
    // +1 tile pad so the depth-1 prefetch can read one-past-end harmlessly
    __shared__ unsigned short sh_hi[(TILES_MAX + 1) * 256];  // 17.4 KB
    __shared__ float          sh_cn[(TILES_MAX + 1) * 16];   // 2.2 KB

    const int lane = threadIdx.x & 63;
    const int wave = threadIdx.x >> 6;
    const int col  = lane & 15;        // A: m-index; C/D: n-index
    const int quad = lane >> 4;
    const int koff = (quad & 1) * 8;   // k-slice within D=16

    const int qg = blockIdx.x * 4 + wave;   // 64 queries per wave

    // ---- this block's n-tile range (tiles of 16 points)
    const int NT = N >> 4;                       // 6250
    const int base = NT / NCHUNK, rem = NT % NCHUNK;
    const int chunk = blockIdx.y;
    const int tile0 = chunk * base + min(chunk, rem);
    const int cnt = base + (chunk < rem ? 1 : 0);
    const int npts = cnt * 16;
    const int n0 = tile0 * 16;

    // ---- stage: fp32 -> bf16 pack + per-point constant, straight into LDS
    for (int p = threadIdx.x; p < npts; p += 256) {
        const float4* dp = (const float4*)(data + (size_t)(n0 + p) * D);
        float4 v0 = dp[0], v1 = dp[1], v2 = dp[2], v3 = dp[3];
        float vv[16] = {v0.x, v0.y, v0.z, v0.w, v1.x, v1.y, v1.z, v1.w,
                        v2.x, v2.y, v2.z, v2.w, v3.x, v3.y, v3.z, v3.w};
        float dd = 0.f;
        unsigned hp[8];
        #pragma unroll
        for (int j = 0; j < 8; j++) {
            float a = vv[2 * j], b = vv[2 * j + 1];
            dd = fmaf(a, a, fmaf(b, b, dd));
            hp[j] = (unsigned)f2bf(a) | ((unsigned)f2bf(b) << 16);
        }
        uint4* dst = (uint4*)(sh_hi + p * 16);
        dst[0] = make_uint4(hp[0], hp[1], hp[2], hp[3]);
        dst[1] = make_uint4(hp[4], hp[5], hp[6], hp[7]);
        sh_cn[p] = fmaf(-0.5f * LOG2E, dd, __builtin_amdgcn_logf(w[n0 + p]));
    }

    // ---- A fragments: bf16(L*x) in quads 0,1; zeros in quads 2,3 (K padding)
    bf16x8 afrag[WQT];
    #pragma unroll
    for (int t = 0; t < WQT; t++) {
        int q = (qg * WQT + t) * 16 + col;
        const float* xp = X + (size_t)q * D + koff;
        bf16x8 a;
        #pragma unroll
        for (int j = 0; j < 8; j++)
            a[j] = (quad < 2) ? (short)f2bf(xp[j] * LOG2E) : (short)0;
        afrag[t] = a;
    }

    float dens[WQT][4];
    #pragma unroll
    for (int t = 0; t < WQT; t++)
        #pragma unroll
        for (int r = 0; r < 4; r++) dens[t][r] = 0.f;

    __syncthreads();

    // ---- main loop: depth-1 LDS prefetch, 4 independent MFMA->exp2 chains
    const int eoff = (col << 4) + koff;          // shorts
    bf16x8 b1 = *(const bf16x8*)(sh_hi + eoff);
    float  c0 = sh_cn[col];
    for (int it = 0; it < cnt; it++) {
        bf16x8 nb1 = *(const bf16x8*)(sh_hi + (it + 1) * 256 + eoff);
        float  nc0 = sh_cn[(it + 1) * 16 + col];
        f32x4 cvec = {c0, c0, c0, c0};
        #pragma unroll
        for (int t = 0; t < WQT; t++) {
            f32x4 s = __builtin_amdgcn_mfma_f32_16x16x32_bf16(afrag[t], b1, cvec, 0, 0, 0);
            #pragma unroll
            for (int r = 0; r < 4; r++)
                dens[t][r] += __builtin_amdgcn_exp2f(s[r]);
        }
        b1 = nb1; c0 = nc0;
    }

    // ---- reduce over the 16 n-lanes, plain store (no atomics)
    #pragma unroll
    for (int t = 0; t < WQT; t++) {
        #pragma unroll
        for (int r = 0; r < 4; r++) {
            float v = dens[t][r];
            v += __shfl_xor(v, 1, 64);
            v += __shfl_xor(v, 2, 64);
            v += __shfl_xor(v, 4, 64);
            v += __shfl_xor(v, 8, 64);
            if (col == 0) {
                int q = (qg * WQT + t) * 16 + quad * 4 + r;
                part[(size_t)chunk * Q + q] = v;
            }
        }
    }
}

// ---------------- finalize: reduce chunks + log density ----------------
__global__ void fin_kernel(const float* __restrict__ X, const float* __restrict__ part,
                           const float* __restrict__ sumw, float* __restrict__ out, int Q) {
    int q = blockIdx.x * blockDim.x + threadIdx.x;
    if (q >= Q) return;
    float a0 = 0.f, a1 = 0.f, a2 = 0.f, a3 = 0.f;
    for (int c = 0; c < NCHUNK; c += 4) {
        a0 += part[(size_t)(c + 0) * Q + q];
        a1 += part[(size_t)(c + 1) * Q + q];
        a2 += part[(size_t)(c + 2) * Q + q];
        a3 += part[(size_t)(c + 3) * Q + q];
    }
    float dsum = (a0 + a1) + (a2 + a3);
    float xx = 0.f;
    #pragma unroll
    for (int k = 0; k < D; k++) {
        float v = X[(size_t)q * D + k];
        xx += v * v;
    }
    float aq = -0.5f * LOG2E * xx;
    const float ln_norm = -8.f * 1.8378770664093453f;  // ln((2*pi)^-8)
    float ld = LN2 * (aq + __builtin_amdgcn_logf(dsum) - __builtin_amdgcn_logf(sumw[0])) + ln_norm;
    out[q] = ld;
}

extern "C" void kernel_launch(void* const* d_in, const int* in_sizes, int n_in,
                              void* d_out, int out_size, void* d_ws, size_t ws_size,
                              hipStream_t stream) {
    const float* X    = (const float*)d_in[0];
    const float* data = (const float*)d_in[1];
    const float* w    = (const float*)d_in[2];
    float* out = (float*)d_out;
    int Q = in_sizes[0] / D;   // 2048
    int N = in_sizes[1] / D;   // 100000

    // ws layout (floats): [0..64) sumw, then part (NCHUNK*Q)
    float* sumw = (float*)d_ws;
    float* part = sumw + 64;

    hipMemsetAsync(d_ws, 0, 64 * sizeof(float), stream);

    sumw_kernel<<<64, 256, 0, stream>>>(w, N, sumw);

    dim3 grid(Q / (4 * WQT * 16), NCHUNK);   // (8, 192)
    dens_kernel<<<grid, 256, 0, stream>>>(X, data, w, part, Q, N);

    fin_kernel<<<(Q + 255) / 256, 256, 0, stream>>>(X, part, sumw, out, Q);
}